// Round 1
// baseline (1662459.375 us; speedup 1.0000x reference)
//
#include <hip/hip_runtime.h>
#include <cstdint>
#include <cstddef>

#define TT 65536
#define KK 512
#define RPREF 16
#define SEG 256
#define NSEG 256  // TT/SEG

typedef unsigned short u16;
typedef unsigned int   u32;
typedef unsigned long long u64;

__device__ __forceinline__ float u2f(u32 b){ union{u32 u; float f;} x; x.u=b; return x.f; }
__device__ __forceinline__ u32 f2u(float f){ union{u32 u; float f;} x; x.f=f; return x.u; }

// ---------------------------------------------------------------------------
// P0: per-row sort of transitions, descending by value, ascending index on ties.
// Output layout row-major: sV[n*KK+k], sP[n*KK+k]. First 16 entries (the top-16
// by value) are re-sorted by p ASCENDING so the scan's strict-> update
// reproduces numpy argmax first-index tie-breaking cheaply.
// ---------------------------------------------------------------------------
__global__ __launch_bounds__(512)
void sort_rows(const float* __restrict__ trans, float* __restrict__ sV, u16* __restrict__ sP)
{
    __shared__ u64 s[KK];
    const int n = blockIdx.x, i = threadIdx.x;
    float x = trans[n*KK + i];
    u32 b = f2u(x);
    u32 ord = (b & 0x80000000u) ? ~b : (b | 0x80000000u);   // monotone u32 of float order
    s[i] = ((u64)(~ord) << 16) | (u32)i;                    // asc sort => value desc, p asc
    __syncthreads();

    for (int k = 2; k <= KK; k <<= 1){
        for (int j = k >> 1; j > 0; j >>= 1){
            int ixj = i ^ j;
            if (ixj > i){
                u64 a = s[i], c = s[ixj];
                bool up = ((i & k) == 0);
                if ((a > c) == up){ s[i] = c; s[ixj] = a; }
            }
            __syncthreads();
        }
    }

    // re-sort first 16 by p ascending (single thread; trivial one-time cost)
    if (i == 0){
        for (int a = 1; a < RPREF; ++a){
            u64 x2 = s[a]; u32 px = (u32)(x2 & 0xFFFFu); int b2 = a - 1;
            while (b2 >= 0 && (u32)(s[b2] & 0xFFFFu) > px){ s[b2+1] = s[b2]; --b2; }
            s[b2+1] = x2;
        }
    }
    __syncthreads();

    u64 key = s[i];
    u32 oi   = (u32)(key >> 16);
    u32 ordv = ~oi;
    u32 bits = (ordv & 0x80000000u) ? (ordv ^ 0x80000000u) : ~ordv;  // invert ord mapping
    sV[n*KK + i] = u2f(bits);                 // exact original float bits
    sP[n*KK + i] = (u16)(key & 0xFFFFu);
}

// ---------------------------------------------------------------------------
// Main scan: 1 block, 512 threads (8 waves), persistent over all T steps.
// Thread i owns tag i. fv double-buffered in LDS; one barrier per step.
// Exact fp32 replication of: scores = fv[None,:]+trans; bp=argmax(first-index);
// fv = max(scores)+feat[t].
// ---------------------------------------------------------------------------
__global__ __launch_bounds__(512)
void viterbi_scan(const float* __restrict__ feats,
                  const float* __restrict__ sV, const u16* __restrict__ sP,
                  u16* __restrict__ bp,
                  float* __restrict__ outScore, int* __restrict__ bestOut)
{
    __shared__ float fvb[2][KK];
    __shared__ float wmax[2][8];
    __shared__ float rv[KK];
    __shared__ int   ri[KK];

    const int i = threadIdx.x;
    const int lane = i & 63, wv = i >> 6;

    // preload top-16 candidates (p-ascending within the top-16-by-value set)
    float cV[RPREF]; int cP[RPREF];
#pragma unroll
    for (int k = 0; k < RPREF; ++k){ cV[k] = sV[i*KK + k]; cP[k] = (int)sP[i*KK + k]; }
    float vmin16 = cV[0], rowmax = cV[0];
#pragma unroll
    for (int k = 1; k < RPREF; ++k){ vmin16 = fminf(vmin16, cV[k]); rowmax = fmaxf(rowmax, cV[k]); }

    // ---- step 0 (init fv = [0, -1e4, ...]; col 0 of trans == -1e4 exactly) ----
    // fv1[n] = max( fl(0 + trans[n,0]) = -1e4 , fl(-1e4 + max_{p>=1} trans[n,p]) ) + feat[0,n]
    float v1 = fmaxf(-10000.0f, -10000.0f + rowmax) + feats[i];
    fvb[1][i] = v1;
    float wm = v1;
#pragma unroll
    for (int o = 32; o > 0; o >>= 1) wm = fmaxf(wm, __shfl_xor(wm, o, 64));
    if (lane == 0) wmax[1][wv] = wm;
    __syncthreads();
    float fvmax = wmax[1][0];
#pragma unroll
    for (int w = 1; w < 8; ++w) fvmax = fmaxf(fvmax, wmax[1][w]);

    float featCur = feats[1*KK + i];

    for (int t = 1; t < TT; ++t){
        const float* fvc = fvb[t & 1];
        float featNxt = feats[(size_t)(t+1 < TT ? t+1 : t)*KK + i];

        float best; int barg;
        if (i == 1){
            // row 1 of trans is all -10000: max_p fl(fv[p]-1e4) == fl(fvmax-1e4) exactly.
            // Its backpointer can never lie on the decoded path (margin ~1e4), so barg free.
            best = fvmax + (-10000.0f); barg = 0;
        } else {
            float val0 = fvc[cP[0]] + cV[0];
            best = val0; barg = cP[0];
#pragma unroll
            for (int k = 1; k < RPREF; ++k){
                float val = fvc[cP[k]] + cV[k];
                bool take = (val > best);            // p-ascending order => strict > == first-index
                best = take ? val : best;
                barg = take ? cP[k] : barg;
            }
            // exact termination bound: unseen candidates have v <= vmin16, and
            // fl(fv[p]+v) <= fl(fvmax+v) <= fl(fvmax+vmin16) by fp-add monotonicity.
            if (fvmax + vmin16 >= best){
                int k = RPREF;
                while (k < KK){
                    float v16[16]; int p16[16];
#pragma unroll
                    for (int j = 0; j < 16; ++j){
                        v16[j] = sV[i*KK + k + j];
                        p16[j] = (int)sP[i*KK + k + j];
                    }
#pragma unroll
                    for (int j = 0; j < 16; ++j){
                        float val = fvc[p16[j]] + v16[j];
                        bool take = (val > best) || (val == best && p16[j] < barg);
                        best = take ? val : best;
                        barg = take ? p16[j] : barg;
                    }
                    k += 16;
                    if (fvmax + v16[15] < best) break;   // strict <: all remaining (and ties) excluded
                }
            }
        }

        float fvnew = best + featCur;
        bp[(size_t)t*KK + i] = (u16)barg;
        fvb[(t+1) & 1][i] = fvnew;

        float wm2 = fvnew;
#pragma unroll
        for (int o = 32; o > 0; o >>= 1) wm2 = fmaxf(wm2, __shfl_xor(wm2, o, 64));
        if (lane == 0) wmax[(t+1) & 1][wv] = wm2;
        __syncthreads();
        float fm = wmax[(t+1) & 1][0];
#pragma unroll
        for (int w = 1; w < 8; ++w) fm = fmaxf(fm, wmax[(t+1) & 1][w]);
        fvmax = fm;
        featCur = featNxt;
    }

    // ---- terminal: terminal[p] = fl(fv_T[p] + (-1e4)) (trans row 1 is all -1e4);
    //      argmax with first-index tie-break; score = terminal[best]. fv_T is in fvb[0].
    float tv = fvb[0][i] + (-10000.0f);
    rv[i] = tv; ri[i] = i;
    __syncthreads();
    for (int s = 256; s > 0; s >>= 1){
        if (i < s){
            float v2 = rv[i+s]; int i2 = ri[i+s];
            if (v2 > rv[i] || (v2 == rv[i] && i2 < ri[i])){ rv[i] = v2; ri[i] = i2; }
        }
        __syncthreads();
    }
    if (i == 0){ outScore[0] = rv[0]; *bestOut = ri[0]; }
}

// ---------------------------------------------------------------------------
// Backtrack: segment maps (parallel) -> boundary tags (sequential, tiny) ->
// per-segment decode (parallel). path[t-1] = bp[t][path[t]], path[T-1]=best.
// ---------------------------------------------------------------------------
__global__ __launch_bounds__(512)
void bt_maps(const u16* __restrict__ bp, u16* __restrict__ maps)
{
    const int s = blockIdx.x, e = threadIdx.x;
    const int tEnd = (s == NSEG-1) ? (TT-1) : (s+1)*SEG;
    const int tLow = s*SEG;
    int cur = e;
    for (int t = tEnd; t > tLow; --t) cur = (int)bp[(size_t)t*KK + cur];
    maps[s*KK + e] = (u16)cur;   // tag at time tLow given tag at time tEnd == e
}

__global__ void bt_boundaries(const u16* __restrict__ maps, const int* __restrict__ bestP,
                              int* __restrict__ btag)
{
    if (threadIdx.x != 0 || blockIdx.x != 0) return;
    int cur = *bestP;                       // tag at time TT-1
    for (int s = NSEG-1; s >= 0; --s){
        cur = (int)maps[s*KK + cur];        // tag at time s*SEG
        btag[s] = cur;
    }
}

__global__ void bt_decode(const u16* __restrict__ bp, const int* __restrict__ btag,
                          const int* __restrict__ bestP, float* __restrict__ outPath)
{
    const int s = blockIdx.x;
    if (threadIdx.x != 0) return;
    int tEnd, cur;
    if (s == NSEG-1){ tEnd = TT-1; cur = *bestP; outPath[TT-1] = (float)cur; }
    else            { tEnd = (s+1)*SEG; cur = btag[s+1]; }
    for (int t = tEnd; t > s*SEG; --t){
        cur = (int)bp[(size_t)t*KK + cur];
        outPath[t-1] = (float)cur;
    }
}

// ---------------------------------------------------------------------------
extern "C" void kernel_launch(void* const* d_in, const int* in_sizes, int n_in,
                              void* d_out, int out_size, void* d_ws, size_t ws_size,
                              hipStream_t stream)
{
    (void)in_sizes; (void)n_in; (void)out_size; (void)ws_size;
    const float* feats = (const float*)d_in[0];
    const float* trans = (const float*)d_in[1];
    float* out = (float*)d_out;

    char* ws = (char*)d_ws;
    size_t off = 0;
    u16*   bp   = (u16*)(ws + off);  off += (size_t)TT*KK*sizeof(u16);    // 64 MB
    float* sV   = (float*)(ws + off); off += (size_t)KK*KK*sizeof(float); // 1 MB
    u16*   sP   = (u16*)(ws + off);  off += (size_t)KK*KK*sizeof(u16);    // 0.5 MB
    u16*   maps = (u16*)(ws + off);  off += (size_t)NSEG*KK*sizeof(u16);  // 256 KB
    int*   btag = (int*)(ws + off);  off += (size_t)(NSEG+8)*sizeof(int);
    int*   bestP= (int*)(ws + off);

    hipLaunchKernelGGL(sort_rows,     dim3(KK),   dim3(512), 0, stream, trans, sV, sP);
    hipLaunchKernelGGL(viterbi_scan,  dim3(1),    dim3(512), 0, stream, feats, sV, sP, bp, out, bestP);
    hipLaunchKernelGGL(bt_maps,       dim3(NSEG), dim3(512), 0, stream, bp, maps);
    hipLaunchKernelGGL(bt_boundaries, dim3(1),    dim3(64),  0, stream, maps, bestP, btag);
    hipLaunchKernelGGL(bt_decode,     dim3(NSEG), dim3(64),  0, stream, bp, btag, bestP, out + 1);
}

// Round 2
// 843094.434 us; speedup vs baseline: 1.9719x; 1.9719x over previous
//
#include <hip/hip_runtime.h>
#include <cstdint>
#include <cstddef>

#define TT 65536
#define KK 512
#define NEGV (-10000.0f)
#define SEG 256
#define NSEG 256  // TT/SEG

typedef unsigned short u16;
typedef unsigned int   u32;
typedef unsigned long long u64;

__device__ __forceinline__ float u2f(u32 b){ union{u32 u; float f;} x; x.u=b; return x.f; }
__device__ __forceinline__ u32 f2u(float f){ union{u32 u; float f;} x; x.f=f; return x.u; }

// ---------------------------------------------------------------------------
// Per-row sort of transitions, desc by value, asc index on ties.
// svp[n*KK+k] = ((u64)p << 32) | float_bits(v)
// ---------------------------------------------------------------------------
__global__ __launch_bounds__(512)
void sort_rows(const float* __restrict__ trans, u64* __restrict__ svp)
{
    __shared__ u64 s[KK];
    const int n = blockIdx.x, i = threadIdx.x;
    float x = trans[n*KK + i];
    u32 b = f2u(x);
    u32 ord = (b & 0x80000000u) ? ~b : (b | 0x80000000u);   // monotone u32 order
    s[i] = ((u64)(~ord) << 16) | (u32)i;                    // asc sort => value desc, p asc
    __syncthreads();
    for (int k = 2; k <= KK; k <<= 1){
        for (int j = k >> 1; j > 0; j >>= 1){
            int ixj = i ^ j;
            if (ixj > i){
                u64 a = s[i], c = s[ixj];
                bool up = ((i & k) == 0);
                if ((a > c) == up){ s[i] = c; s[ixj] = a; }
            }
            __syncthreads();
        }
    }
    u64 key = s[i];
    u32 p    = (u32)(key & 0xFFFFu);
    u32 ordv = ~(u32)(key >> 16);
    u32 bits = (ordv & 0x80000000u) ? (ordv ^ 0x80000000u) : ~ordv;
    svp[(size_t)n*KK + i] = ((u64)p << 32) | bits;
}

// transT[p*KK + n] = trans[n*KK + p]  (so gather trans[n,p] is lane-coalesced in n)
__global__ __launch_bounds__(512)
void transpose_k(const float* __restrict__ t, float* __restrict__ tt)
{
    const int c = blockIdx.x, r = threadIdx.x;
    tt[(size_t)c*KK + r] = t[(size_t)r*KK + c];
}

// ---------------------------------------------------------------------------
// Main scan: 1 block, 512 threads. Thread i owns tag i.
// Pruning: fv-band masks (ballot at fvmax - {0.75,1.5,2.5,4.0}) + register
// top-64 v-sorted candidates, cross-bound termination fl(B_band + v_k) < best.
// All bounds exact via fp-add monotonicity; 3-way cmp = numpy first-index ties.
// ---------------------------------------------------------------------------
__global__ __launch_bounds__(512, 2)
void viterbi_scan(const float* __restrict__ feats,
                  const u64* __restrict__ svp,
                  const float* __restrict__ transT,
                  u16* __restrict__ bp,
                  float* __restrict__ outScore, int* __restrict__ bestOut)
{
    __shared__ float fvb[2][KK];
    __shared__ float wmaxS[2][8];
    __shared__ u64  bmS[2][4][8];
    __shared__ float rv[KK];
    __shared__ int   ri[KK];

    const int i = threadIdx.x;
    const int lane = i & 63, wv = i >> 6;

    // top-64 (v,p) candidates for own row, v desc. p packed 2x16b per reg.
    float cV[64]; u32 cPp[32];
#pragma unroll
    for (int k = 0; k < 32; ++k){
        u64 e0 = svp[(size_t)i*KK + 2*k];
        u64 e1 = svp[(size_t)i*KK + 2*k + 1];
        cV[2*k]   = u2f((u32)e0);
        cV[2*k+1] = u2f((u32)e1);
        cPp[k] = ((u32)(e0 >> 32) & 0xFFFFu) | (((u32)(e1 >> 32) & 0xFFFFu) << 16);
    }

    // ---- step 0 closed form: fv init = [0, NEG...]; col0 of trans = NEG ----
    float v1 = fmaxf(NEGV, NEGV + cV[0]) + feats[i];
    fvb[1][i] = v1;
    float wm = v1;
#pragma unroll
    for (int o = 32; o > 0; o >>= 1) wm = fmaxf(wm, __shfl_xor(wm, o, 64));
    if (lane == 0) wmaxS[1][wv] = wm;
    __syncthreads();
    float fvmax = wmaxS[1][0];
#pragma unroll
    for (int w = 1; w < 8; ++w) fvmax = fmaxf(fvmax, wmaxS[1][w]);
    {
        u64 q0 = __ballot(v1 > fvmax - 0.75f);
        u64 q1 = __ballot(v1 > fvmax - 1.5f);
        u64 q2 = __ballot(v1 > fvmax - 2.5f);
        u64 q3 = __ballot(v1 > fvmax - 4.0f);
        if (lane == 0){
            bmS[1][0][wv] = q0;
            bmS[1][1][wv] = q1 & ~q0;
            bmS[1][2][wv] = q2 & ~q1;
            bmS[1][3][wv] = q3 & ~q2;
        }
    }
    __syncthreads();

    float featCur = feats[(size_t)1*KK + i];

    for (int t = 1; t < TT; ++t){
        const int cur = t & 1, nxt = (t+1) & 1;
        const float* fvc = fvb[cur];
        float featNxt = __builtin_nontemporal_load(
            &feats[(size_t)(t+1 < TT ? t+1 : t)*KK + i]);

        float best = -3.0e38f; int barg = 0;
        if (i == 1){
            // row 1 all NEG: max_p fl(fv[p]+NEG) == fl(fvmax+NEG); bp never on path
            best = fvmax + NEGV; barg = 0;
        } else {
            const float B1f = fvmax - 1.5f;
            const float B2f = fvmax - 2.5f;
            const float B3f = fvmax - 4.0f;

            // bands 0,1: all tags with fv > fvmax-1.5 (explicit, coalesced gathers)
#pragma unroll
            for (int b = 0; b < 2; ++b){
#pragma unroll
                for (int w = 0; w < 8; ++w){
                    u64 m = bmS[cur][b][w];
                    while (m){
                        int bit = __builtin_ctzll(m); m &= m - 1;
                        int p = w*64 + bit;
                        float val = fvc[p] + transT[(size_t)p*KK + i];
                        bool take = (val > best) || (val == best && p < barg);
                        best = take ? val : best; barg = take ? p : barg;
                    }
                }
            }
            bool done = (B1f + cV[0] < best);
            float Bcur = B1f;

#define VCHUNK(c) \
            if (!done){ \
                _Pragma("unroll") \
                for (int j = 0; j < 8; ++j){ \
                    const int k = (c)*8 + j; \
                    int p = (int)((cPp[k>>1] >> ((k&1)*16)) & 0xFFFFu); \
                    float val = fvc[p] + cV[k]; \
                    bool take = (val > best) || (val == best && p < barg); \
                    best = take ? val : best; barg = take ? p : barg; \
                } \
                done = (Bcur + cV[(c)*8+7] < best); \
            }

            // deeper band eval with per-word early exit; bound uses PREVIOUS band's B
            auto bandEval = [&](int b, float Bprev, float vguard){
#pragma unroll
                for (int w = 0; w < 8; ++w){
                    if (!done){
                        u64 m = bmS[cur][b][w];
                        while (m){
                            int bit = __builtin_ctzll(m); m &= m - 1;
                            int p = w*64 + bit;
                            float val = fvc[p] + transT[(size_t)p*KK + i];
                            bool take = (val > best) || (val == best && p < barg);
                            best = take ? val : best; barg = take ? p : barg;
                        }
                        done = (Bprev + vguard < best);
                    }
                }
            };

            VCHUNK(0) VCHUNK(1) VCHUNK(2) VCHUNK(3)
            if (!done){
                bandEval(2, B1f, cV[31]);
                Bcur = B2f;
                done = (B2f + cV[31] < best);
            }
            VCHUNK(4) VCHUNK(5)
            if (!done){
                bandEval(3, B2f, cV[47]);
                Bcur = B3f;
                done = (B3f + cV[47] < best);
            }
            VCHUNK(6) VCHUNK(7)
#undef VCHUNK
            // rare continuation: stream own sorted row from global, bound B3
            int kc = 64;
            while (!done && kc < KK){
#pragma unroll
                for (int j = 0; j < 8; ++j){
                    u64 e = svp[(size_t)i*KK + kc + j];
                    float vv = u2f((u32)e); int pp = (int)(e >> 32);
                    float val = fvc[pp] + vv;
                    bool take = (val > best) || (val == best && pp < barg);
                    best = take ? val : best; barg = take ? pp : barg;
                    if (j == 7) done = (B3f + vv < best);
                }
                kc += 8;
            }
        }

        float fvnew = best + featCur;
        __builtin_nontemporal_store((u16)barg, &bp[(size_t)t*KK + i]);
        fvb[nxt][i] = fvnew;
        float wm2 = fvnew;
#pragma unroll
        for (int o = 32; o > 0; o >>= 1) wm2 = fmaxf(wm2, __shfl_xor(wm2, o, 64));
        if (lane == 0) wmaxS[nxt][wv] = wm2;
        __syncthreads();                       // A: fv/wmax visible
        float fm = wmaxS[nxt][0];
#pragma unroll
        for (int w = 1; w < 8; ++w) fm = fmaxf(fm, wmaxS[nxt][w]);
        {
            u64 q0 = __ballot(fvnew > fm - 0.75f);
            u64 q1 = __ballot(fvnew > fm - 1.5f);
            u64 q2 = __ballot(fvnew > fm - 2.5f);
            u64 q3 = __ballot(fvnew > fm - 4.0f);
            if (lane == 0){
                bmS[nxt][0][wv] = q0;
                bmS[nxt][1][wv] = q1 & ~q0;
                bmS[nxt][2][wv] = q2 & ~q1;
                bmS[nxt][3][wv] = q3 & ~q2;
            }
        }
        fvmax = fm;
        featCur = featNxt;
        __syncthreads();                       // B: band masks visible
    }

    // ---- terminal: terminal[p] = fl(fv_T[p] + NEG); first-index argmax ----
    float tv = fvb[0][i] + NEGV;
    rv[i] = tv; ri[i] = i;
    __syncthreads();
    for (int s2 = 256; s2 > 0; s2 >>= 1){
        if (i < s2){
            float v2 = rv[i+s2]; int i2 = ri[i+s2];
            if (v2 > rv[i] || (v2 == rv[i] && i2 < ri[i])){ rv[i] = v2; ri[i] = i2; }
        }
        __syncthreads();
    }
    if (i == 0){ outScore[0] = rv[0]; *bestOut = ri[0]; }
}

// ---------------------------------------------------------------------------
// Backtrack: segment maps (parallel) -> boundary tags -> per-segment decode.
// ---------------------------------------------------------------------------
__global__ __launch_bounds__(512)
void bt_maps(const u16* __restrict__ bp, u16* __restrict__ maps)
{
    const int s = blockIdx.x, e = threadIdx.x;
    const int tEnd = (s == NSEG-1) ? (TT-1) : (s+1)*SEG;
    const int tLow = s*SEG;
    int cur = e;
    for (int t = tEnd; t > tLow; --t) cur = (int)bp[(size_t)t*KK + cur];
    maps[s*KK + e] = (u16)cur;
}

__global__ void bt_boundaries(const u16* __restrict__ maps, const int* __restrict__ bestP,
                              int* __restrict__ btag)
{
    if (threadIdx.x != 0 || blockIdx.x != 0) return;
    int cur = *bestP;
    for (int s = NSEG-1; s >= 0; --s){
        cur = (int)maps[s*KK + cur];
        btag[s] = cur;
    }
}

__global__ void bt_decode(const u16* __restrict__ bp, const int* __restrict__ btag,
                          const int* __restrict__ bestP, float* __restrict__ outPath)
{
    const int s = blockIdx.x;
    if (threadIdx.x != 0) return;
    int tEnd, cur;
    if (s == NSEG-1){ tEnd = TT-1; cur = *bestP; outPath[TT-1] = (float)cur; }
    else            { tEnd = (s+1)*SEG; cur = btag[s+1]; }
    for (int t = tEnd; t > s*SEG; --t){
        cur = (int)bp[(size_t)t*KK + cur];
        outPath[t-1] = (float)cur;
    }
}

// ---------------------------------------------------------------------------
extern "C" void kernel_launch(void* const* d_in, const int* in_sizes, int n_in,
                              void* d_out, int out_size, void* d_ws, size_t ws_size,
                              hipStream_t stream)
{
    (void)in_sizes; (void)n_in; (void)out_size; (void)ws_size;
    const float* feats = (const float*)d_in[0];
    const float* trans = (const float*)d_in[1];
    float* out = (float*)d_out;

    char* ws = (char*)d_ws;
    size_t off = 0;
    u16*   bp    = (u16*)(ws + off);   off += (size_t)TT*KK*sizeof(u16);   // 64 MB
    u64*   svp   = (u64*)(ws + off);   off += (size_t)KK*KK*sizeof(u64);   // 2 MB
    float* transT= (float*)(ws + off); off += (size_t)KK*KK*sizeof(float); // 1 MB
    u16*   maps  = (u16*)(ws + off);   off += (size_t)NSEG*KK*sizeof(u16); // 256 KB
    int*   btag  = (int*)(ws + off);   off += (size_t)(NSEG+8)*sizeof(int);
    int*   bestP = (int*)(ws + off);

    hipLaunchKernelGGL(sort_rows,     dim3(KK),   dim3(512), 0, stream, trans, svp);
    hipLaunchKernelGGL(transpose_k,   dim3(KK),   dim3(512), 0, stream, trans, transT);
    hipLaunchKernelGGL(viterbi_scan,  dim3(1),    dim3(512), 0, stream, feats, svp, transT, bp, out, bestP);
    hipLaunchKernelGGL(bt_maps,       dim3(NSEG), dim3(512), 0, stream, bp, maps);
    hipLaunchKernelGGL(bt_boundaries, dim3(1),    dim3(64),  0, stream, maps, bestP, btag);
    hipLaunchKernelGGL(bt_decode,     dim3(NSEG), dim3(64),  0, stream, bp, btag, bestP, out + 1);
}